// Round 9
// baseline (284.005 us; speedup 1.0000x reference)
//
#include <hip/hip_runtime.h>
#include <stdint.h>

// Problem: B=4, S=2048, D=1024, H=16, HD=64. I/O fp32; internal compute bf16
// MFMA with fp32 accumulation.
// SCALE*log2(e) folded into wq^T and bq -> flash uses exp2 directly with a
// FIXED softmax max of 0 (shift-invariant; logits statically bounded ~|9|).
// Flash lineage: R9 (99.7) 16x16 reg-P. R12 setprio+dbuf REGRESSED (110.2).
// R13 2x occupancy: null. R14 32x32x16 MFMA (106.5): -67% MFMA instr -> null.
// R15 T14 async reg-staging (93.7, -12% CONFIRMED): exposed vmcnt drain was
// the stall. R16 64 q/wave halved LDS-per-FLOP: null (paid back by losing
// 2 blocks/CU overlap). Pipe audit: MFMA 7%/SIMD, VALU 12%/SIMD, LDS 30%/CU,
// ~50% lockstep/latency stall.
// R17 (2nd submit; R8 bench was an infra failure -- same error previously hit
// the known-good R0 kernel; V-image write/read math re-audited, all offsets
// in bounds): V image redesign -> fragment-direct b128 layout.
// Per 64-s chunk: [slice(4)][hi(2)][d(64)][8 s] so a PV A-frag is ONE
// coalesced conflict-free b128 read with k-slots already in pi-order
// (j<4 <-> s_rem=4hi+j; j>=4 <-> s_rem=8+4hi+j-4). V reads 16xb64 -> 8xb128
// per wave-iter; slot-rotation VALU deleted; V bank conflicts -> 0.
// gemm<0> V-epilogue writes the new image (same single 8B store, new offset).
// Everything else frozen (K path, staging, barriers, grid, gemm<1>).

typedef __attribute__((ext_vector_type(8))) short bf16x8;
typedef __attribute__((ext_vector_type(4))) short bf16x4;
typedef __attribute__((ext_vector_type(4))) float f32x4;
typedef __attribute__((ext_vector_type(16))) float f32x16;
typedef __attribute__((ext_vector_type(4))) int i32x4;
typedef unsigned short u16;
typedef unsigned int u32;

#define AS1 __attribute__((address_space(1)))
#define AS3 __attribute__((address_space(3)))

#define SCALE_L2E 0.18033688011112042f  // 0.125 * log2(e)

__device__ __forceinline__ void gld_lds16(const void* g, void* l) {
  // async global->LDS DMA: lane i's 16B land at (wave-uniform) l + i*16
  __builtin_amdgcn_global_load_lds((const AS1 void*)g, (AS3 void*)l, 16, 0, 0);
}

__device__ __forceinline__ u16 f2bf(float f) {
  u32 x = __builtin_bit_cast(u32, f);
  x += 0x7fff + ((x >> 16) & 1);  // RNE
  return (u16)(x >> 16);
}

__device__ __forceinline__ u16 f2bf_fast(float a) {
#if __has_builtin(__builtin_amdgcn_cvt_pk_bf16_f32)
  auto v = __builtin_amdgcn_cvt_pk_bf16_f32(a, a);  // both halves = a: order-immune
  return (u16)(__builtin_bit_cast(u32, v) & 0xffffu);
#else
  return f2bf(a);
#endif
}

__device__ __forceinline__ u32 pk2(float a, float b) {  // lo16=a, hi16=b
#if __has_builtin(__builtin_amdgcn_cvt_pk_bf16_f32)
  return __builtin_bit_cast(u32, __builtin_amdgcn_cvt_pk_bf16_f32(a, b));
#else
  return (u32)f2bf(a) | ((u32)f2bf(b) << 16);
#endif
}

__device__ __forceinline__ float exp2_fast(float x) {
#if __has_builtin(__builtin_amdgcn_exp2f)
  return __builtin_amdgcn_exp2f(x);
#else
  return exp2f(x);
#endif
}

__device__ __forceinline__ f32x16 zero16() {
  f32x16 z;
#pragma unroll
  for (int i = 0; i < 16; ++i) z[i] = 0.f;
  return z;
}

// ---------------------------------------------------------------------------
// fp32 -> bf16 conversion of x (8M elements)
// ---------------------------------------------------------------------------
__global__ __launch_bounds__(256) void convert_x(const float* __restrict__ x,
                                                 u16* __restrict__ xb) {
  int i = (blockIdx.x * 256 + threadIdx.x) * 4;
  float4 v = *(const float4*)(x + i);
  ushort4 o;
  o.x = f2bf(v.x); o.y = f2bf(v.y); o.z = f2bf(v.z); o.w = f2bf(v.w);
  *(ushort4*)(xb + i) = o;
}

// ---------------------------------------------------------------------------
// Weight pack (fp32 [K][N] -> bf16 [N][K]); wq scaled by SCALE*log2(e)
// ---------------------------------------------------------------------------
__global__ __launch_bounds__(256) void pack_weights(
    const float* __restrict__ wq, const float* __restrict__ wk,
    const float* __restrict__ wv, const float* __restrict__ wo,
    u16* __restrict__ wt_qkv, u16* __restrict__ wt_o) {
  __shared__ float tile[64][65];
  int mat = blockIdx.z;
  const float* src = (mat == 0) ? wq : (mat == 1) ? wk : (mat == 2) ? wv : wo;
  int k0 = blockIdx.y * 64, j0 = blockIdx.x * 64;
  int t = threadIdx.x;
  int lr = t >> 6;   // 0..3
  int lc = t & 63;
#pragma unroll
  for (int it = 0; it < 16; ++it) {
    int r = it * 4 + lr;
    tile[r][lc] = src[(size_t)(k0 + r) * 1024 + j0 + lc];
  }
  __syncthreads();
  u16* dst = (mat == 3) ? wt_o : (wt_qkv + (size_t)mat * 1024 * 1024);
#pragma unroll
  for (int it = 0; it < 16; ++it) {
    int nl = it * 4 + lr;
    float v = tile[lc][nl];
    if (mat == 0) v *= SCALE_L2E;  // fold attention scale + log2(e)
    dst[(size_t)(j0 + nl) * 1024 + k0 + lc] = f2bf(v);
  }
}

// ---------------------------------------------------------------------------
// GEMM: C[M,N] = A[M,1024](bf16) x Bt[N,1024]^T(bf16) + bias(fp32).
// 128x128 tile, 4 waves 2x2, each wave 4x4 of 16x16x32 bf16 MFMA (m97 struct).
// 1D grid, XCD-swizzled for L2 locality.
// MODE 0: N=3072 fused QKV.
//   Q,K -> row-major [B,S,D] bf16 (coalesced stores, same addressing as MODE 1)
//   V   -> fragment-direct chunked image for flash (per bh, 64-s chunk ci:
//          [slice(4)][hi(2)][d(64)][8 s-entries] bf16; entry holds
//          V[s = ci*64+slice*16 + {4hi..4hi+3, 8+4hi..8+4hi+3}][d] in order).
// MODE 1: N=1024; plain row-major fp32 out + bias
// NOTE: no dbuf/prefetch here on purpose — m99/m100 measured explicit dbuf
// neutral on this structure (3-block TLP already hides staging latency).
// ---------------------------------------------------------------------------
template <int MODE>
__global__ __launch_bounds__(256, 2) void gemm_bt(
    const u16* __restrict__ A, const u16* __restrict__ Bt,
    const float* __restrict__ bias0, const float* __restrict__ bias1,
    const float* __restrict__ bias2,
    void* __restrict__ out0v, void* __restrict__ out1v, void* __restrict__ out2v) {
  __shared__ u16 lA[128 * 32];  // [m][k] rows of 32 bf16 (64B)
  __shared__ u16 lB[128 * 32];  // [n][k]
  const int K = 1024;
  int tid = threadIdx.x;
  int wave = tid >> 6, lane = tid & 63;

  int bid = blockIdx.x;
  int m0, n0;
  if constexpr (MODE == 0) {
    int xcd = bid & 7, j = bid >> 3;      // 192 blocks per XCD
    n0 = (xcd * 3 + j % 3) * 128;         // XCD owns n-tiles 3x..3x+2 (768KB B)
    m0 = (j / 3) * 128;                   // consecutive j share m-tile
  } else {
    n0 = (bid & 7) * 128;                 // XCD owns 1 n-tile (256KB B)
    m0 = (bid >> 3) * 128;
  }
  int wm = (wave & 1) * 64, wn = (wave >> 1) * 64;

  f32x4 acc[4][4];
#pragma unroll
  for (int i = 0; i < 4; ++i)
#pragma unroll
    for (int j = 0; j < 4; ++j) acc[i][j] = f32x4{0.f, 0.f, 0.f, 0.f};

  int srow = lane >> 2;          // source row within 16-row stage
  int scol = (lane & 3) * 8;     // source col chunk within 32

  for (int k0 = 0; k0 < K; k0 += 32) {
#pragma unroll
    for (int c = 0; c < 2; ++c) {
      int rbase = wave * 32 + c * 16;
      gld_lds16(A + (size_t)(m0 + rbase + srow) * K + k0 + scol, lA + rbase * 32);
      gld_lds16(Bt + (size_t)(n0 + rbase + srow) * K + k0 + scol, lB + rbase * 32);
    }
    __syncthreads();
    bf16x8 af[4], bfr[4];
#pragma unroll
    for (int mt = 0; mt < 4; ++mt)
      af[mt] = *(const bf16x8*)(lA + (wm + mt * 16 + (lane & 15)) * 32 + (lane >> 4) * 8);
#pragma unroll
    for (int nt = 0; nt < 4; ++nt)
      bfr[nt] = *(const bf16x8*)(lB + (wn + nt * 16 + (lane & 15)) * 32 + (lane >> 4) * 8);
#pragma unroll
    for (int mt = 0; mt < 4; ++mt)
#pragma unroll
      for (int nt = 0; nt < 4; ++nt)
        acc[mt][nt] = __builtin_amdgcn_mfma_f32_16x16x32_bf16(af[mt], bfr[nt], acc[mt][nt], 0, 0, 0);
    __syncthreads();
  }

  // epilogue: C/D layout row=(lane>>4)*4+r, col=lane&15 (m89-verified)
  int rbase0 = m0 + wm + (lane >> 4) * 4;
  int cbase = n0 + wn + (lane & 15);
#pragma unroll
  for (int nt = 0; nt < 4; ++nt) {
    int col = cbase + nt * 16;
    if constexpr (MODE == 0) {
      int mat = col >> 10, j = col & 1023;
      const float* bp = (mat == 0) ? bias0 : (mat == 1) ? bias1 : bias2;
      float bv = bp[j];
      if (mat == 0) bv *= SCALE_L2E;
      if (mat == 2) {
        // V fragment-direct image: 4 consecutive s per lane -> one 8B half-entry
        // offset (u16) = bh*131072 + ci*4096 + slice*1024 + hi*512 + d*8 + half*4
        // where s_loc = s&63, slice = s_loc>>4, srem = s_loc&15 (mult of 4),
        // hi = (srem>>2)&1, half = srem>>3, d = hd.
        int h = j >> 6, hd = j & 63;
        u16* base = (u16*)out2v;
#pragma unroll
        for (int mt = 0; mt < 4; ++mt) {
          int row0 = rbase0 + mt * 16;  // multiple of 4, no b/s crossing
          int b = row0 >> 11, s = row0 & 2047;
          int ci = s >> 6, sl = s & 63;
          int slice = sl >> 4, srem = sl & 15;   // srem in {0,4,8,12}
          size_t off = (size_t)(b * 16 + h) * 131072 + ci * 4096 + slice * 1024
                     + ((srem >> 2) & 1) * 512 + hd * 8 + (srem >> 3) * 4;
          ushort4 pk;
          pk.x = f2bf_fast(acc[mt][nt][0] + bv);
          pk.y = f2bf_fast(acc[mt][nt][1] + bv);
          pk.z = f2bf_fast(acc[mt][nt][2] + bv);
          pk.w = f2bf_fast(acc[mt][nt][3] + bv);
          *(ushort4*)(base + off) = pk;
        }
      } else {
        // Q,K row-major [B,S,D]: coalesced (consecutive lanes -> consecutive j)
        u16* base = (mat == 0) ? (u16*)out0v : (u16*)out1v;
#pragma unroll
        for (int mt = 0; mt < 4; ++mt)
#pragma unroll
          for (int r = 0; r < 4; ++r) {
            int row = rbase0 + mt * 16 + r;
            base[(size_t)row * 1024 + j] = f2bf_fast(acc[mt][nt][r] + bv);
          }
      }
    } else {
      float bv = bias0[col];
      float* o = (float*)out0v;
#pragma unroll
      for (int mt = 0; mt < 4; ++mt)
#pragma unroll
        for (int r = 0; r < 4; ++r) {
          int row = rbase0 + mt * 16 + r;
          o[(size_t)row * 1024 + col] = acc[mt][nt][r] + bv;
        }
    }
  }
}

// ---------------------------------------------------------------------------
// Flash attention (R17): 32x32x16 MFMA + T14 async reg-staging + 64 q/wave
// + fragment-direct V image (b128 PV reads).
// Grid 256 (1 block/CU): block = (bh, 512 q-rows), 8 waves x 64 q.
// Per KV-64 iter:
//   issue global_load(t+1) -> VGPRs (K pre-swizzled source, V image linear)
//   compute(t): 2 s-32 blocks sb:
//     kf[4] read ONCE, feeds both q-tiles (qt=0,1): sa0/sa1 via 8 MFMA
//     P = exp2 in regs (per qt), packed to pu[qt][ss]
//     PV per 16-s slice ss, per d-half dh: ONE b128 V-frag read
//       (lV + (sb*2+ss)*1024 + hi*512 + (dh*32+ql)*8), already in pi-order;
//       2 MFMA (qt)
//   __syncthreads(); ds_write regs -> LDS (t+1); __syncthreads()
// Fixed-max softmax (max=0), final lsum reduce = 1 shfl_xor(32).
// ---------------------------------------------------------------------------
__global__ __launch_bounds__(512, 2) void flash_attn(
    const u16* __restrict__ Q, const u16* __restrict__ Kb,
    const u16* __restrict__ Vg, u16* __restrict__ ctx) {
  __shared__ u16 lK[2][64 * 32];  // [k-half][kv-row][32] xor-swizzled (8KB)
  __shared__ u16 lV[4096];        // fragment-direct image [slice][hi][d][8] (8KB)
  int tid = threadIdx.x, wave = tid >> 6, lane = tid & 63;  // wave 0..7

  int F = blockIdx.x;             // 256 flat blocks
  int xcd = F & 7, idx = F >> 3;  // 32 per XCD
  int bh = xcd * 8 + (idx >> 2);  // 8 bh per XCD; q-blocks of a bh adjacent
  int q0 = (idx & 3) * 512;
  int b = bh >> 4, h = bh & 15;
  const u16* Qp = Q + (size_t)b * 2048 * 1024 + h * 64;   // row-major head slice
  const u16* Kp = Kb + (size_t)b * 2048 * 1024 + h * 64;
  const u16* Vp = Vg + (size_t)bh * 131072;

  int ql = lane & 31;   // q (and K-row / V-d row) within 32-block
  int hi = lane >> 5;   // lane half

  // Q B-fragments (persistent): qf[qt][kk] = Q[q0+wave*64+qt*32+ql][kk*16+hi*8+j]
  bf16x8 qf[2][4];
#pragma unroll
  for (int qt = 0; qt < 2; ++qt) {
    const u16* qrow = Qp + (size_t)(q0 + wave * 64 + qt * 32 + ql) * 1024;
#pragma unroll
    for (int kk = 0; kk < 4; ++kk)
      qf[qt][kk] = *(const bf16x8*)(qrow + kk * 16 + hi * 8);
  }

  float lsum[2] = {0.f, 0.f};
  f32x16 o[2][2];  // [qt][dh]: O^T row d=32*dh+(r&3)+8*(r>>2)+4*hi, col q=ql
#pragma unroll
  for (int qt = 0; qt < 2; ++qt)
#pragma unroll
    for (int dh = 0; dh < 2; ++dh) o[qt][dh] = zero16();

  // Staging (T14 reg-staged; split over 8 waves, same layout as old DMA):
  // wave stages K half kk_w, rows rb*16..+16; lane covers row srow, chunk-pos
  // lane&3; source chunk = pos ^ ((row%16)>>1 & 3) (XOR swizzle); V linear.
  int srow = lane >> 2;
  int schunk = (((lane & 3) ^ ((lane >> 3) & 3)) * 8);
  int kk_w = wave & 1;
  int rb = wave >> 1;      // 0..3
  int stg_row = rb * 16 + srow;
  int rkey = ((lane & 15) >> 1) & 3;  // read-side swizzle key (row%16 == lane&15)

  const u16* gK = Kp + (size_t)stg_row * 1024 + kk_w * 32 + schunk;  // +s0*1024
  const u16* gV = Vp + wave * 512 + lane * 8;                        // +s0*64
  u16* wK = lK[kk_w] + rb * 512 + lane * 8;  // lane's 16B at base+lane*16 (u16*8)
  u16* wV = lV + wave * 512 + lane * 8;

  // prologue: tile 0 regs -> LDS
  i32x4 ldK = *(const i32x4*)gK;
  i32x4 ldV = *(const i32x4*)gV;
  *(i32x4*)wK = ldK;
  *(i32x4*)wV = ldV;
  __syncthreads();

  for (int s0 = 0; s0 < 2048; s0 += 64) {
    bool more = (s0 + 64 < 2048);  // wave-uniform
    if (more) {
      // issue t+1 loads now; latency hides under compute(t)
      ldK = *(const i32x4*)(gK + (size_t)(s0 + 64) * 1024);
      ldV = *(const i32x4*)(gV + (size_t)(s0 + 64) * 64);
    }

#pragma unroll
    for (int sb = 0; sb < 2; ++sb) {
      // K A-fragments (read once, feed both q-tiles):
      // lane holds s-row = sb*32+ql, k = kk*16 + hi*8 + j
      bf16x8 kf[4];
      int krb = (sb * 32 + ql) * 32;  // row base (u16)
#pragma unroll
      for (int kk = 0; kk < 4; ++kk)
        kf[kk] = *(const bf16x8*)(lK[kk >> 1] + krb + ((((kk & 1) << 1) | hi) ^ rkey) * 8);

      f32x16 sa0 = zero16(), sa1 = zero16();
#pragma unroll
      for (int kk = 0; kk < 4; ++kk) {
        sa0 = __builtin_amdgcn_mfma_f32_32x32x16_bf16(kf[kk], qf[0][kk], sa0, 0, 0, 0);
        sa1 = __builtin_amdgcn_mfma_f32_32x32x16_bf16(kf[kk], qf[1][kk], sa1, 0, 0, 0);
      }

      // softmax (fixed max 0, log2 units): reg r -> s_local = (r&3)+8*(r>>2)+4*hi
      // pack per qt into pu[qt][ss] (B-frag, register-native pi order)
      bf16x8 pu[2][2];
#pragma unroll
      for (int qt = 0; qt < 2; ++qt) {
        float p[16];
#pragma unroll
        for (int r = 0; r < 16; ++r)
          p[r] = exp2_fast(qt == 0 ? sa0[r] : sa1[r]);
        float a0 = (p[0] + p[1]) + (p[2] + p[3]);
        float a1 = (p[4] + p[5]) + (p[6] + p[7]);
        float a2 = (p[8] + p[9]) + (p[10] + p[11]);
        float a3 = (p[12] + p[13]) + (p[14] + p[15]);
        lsum[qt] += (a0 + a1) + (a2 + a3);
#pragma unroll
        for (int ss = 0; ss < 2; ++ss) {
          union { u32 w[4]; bf16x8 v; } pk_;
          pk_.w[0] = pk2(p[8 * ss + 0], p[8 * ss + 1]);
          pk_.w[1] = pk2(p[8 * ss + 2], p[8 * ss + 3]);
          pk_.w[2] = pk2(p[8 * ss + 4], p[8 * ss + 5]);
          pk_.w[3] = pk2(p[8 * ss + 6], p[8 * ss + 7]);
          pu[qt][ss] = pk_.v;
        }
      }

      // PV: per 16-s slice ss, per d-half dh: ONE b128 A-frag read from the
      // fragment-direct image (pi-order k-slots match register-native P).
#pragma unroll
      for (int ss = 0; ss < 2; ++ss) {
        int vbase = (sb * 2 + ss) * 1024 + hi * 512 + ql * 8;
#pragma unroll
        for (int dh = 0; dh < 2; ++dh) {
          bf16x8 vf = *(const bf16x8*)(lV + vbase + dh * 256);
          o[0][dh] = __builtin_amdgcn_mfma_f32_32x32x16_bf16(vf, pu[0][ss], o[0][dh], 0, 0, 0);
          o[1][dh] = __builtin_amdgcn_mfma_f32_32x32x16_bf16(vf, pu[1][ss], o[1][dh], 0, 0, 0);
        }
      }
    }

    __syncthreads();   // all waves done reading tile t; t+1 loads retired
    if (more) {
      *(i32x4*)wK = ldK;
      *(i32x4*)wV = ldV;
    }
    __syncthreads();   // t+1 LDS writes visible
  }

  // epilogue: lsum pairs live on lanes l and l^32 (same q) -> one shfl_xor;
  // normalize, write ctx[b][q][h][d], d = 32*dh + 8*(r>>2) + 4*hi + (r&3)
#pragma unroll
  for (int qt = 0; qt < 2; ++qt) {
    float rs = lsum[qt] + __shfl_xor(lsum[qt], 32);
    float inv = 1.0f / fmaxf(rs, 1e-30f);
    int q = q0 + wave * 64 + qt * 32 + ql;
    size_t rowbase = ((size_t)(b * 2048 + q) * 16 + h) * 64;
#pragma unroll
    for (int dh = 0; dh < 2; ++dh)
#pragma unroll
      for (int rr = 0; rr < 4; ++rr) {
        ushort4 pk;
        pk.x = f2bf_fast(o[qt][dh][4 * rr + 0] * inv);
        pk.y = f2bf_fast(o[qt][dh][4 * rr + 1] * inv);
        pk.z = f2bf_fast(o[qt][dh][4 * rr + 2] * inv);
        pk.w = f2bf_fast(o[qt][dh][4 * rr + 3] * inv);
        *(ushort4*)(ctx + rowbase + dh * 32 + rr * 8 + hi * 4) = pk;
      }
  }
}

// ---------------------------------------------------------------------------
extern "C" void kernel_launch(void* const* d_in, const int* in_sizes, int n_in,
                              void* d_out, int out_size, void* d_ws, size_t ws_size,
                              hipStream_t stream) {
  const float* x  = (const float*)d_in[0];
  const float* wq = (const float*)d_in[1];
  const float* bq = (const float*)d_in[2];
  const float* wk = (const float*)d_in[3];
  const float* bk = (const float*)d_in[4];
  const float* wv = (const float*)d_in[5];
  const float* bv = (const float*)d_in[6];
  const float* wo = (const float*)d_in[7];
  const float* bo = (const float*)d_in[8];

  u16* ws = (u16*)d_ws;
  u16* xb     = ws;                            // 8192*1024 bf16 (16MB)
  u16* wt_qkv = xb + (size_t)8192 * 1024;      // 3072*1024 (6MB)
  u16* wt_o   = wt_qkv + (size_t)3072 * 1024;  // 1024*1024 (2MB)
  u16* Qb     = wt_o + (size_t)1024 * 1024;    // row-major [B,S,D] (16MB)
  u16* Kbuf   = Qb + (size_t)8192 * 1024;      // row-major [B,S,D] (16MB)
  u16* Vgb    = Kbuf + (size_t)8192 * 1024;    // fragment-direct image (16MB)
  u16* ctx    = Vgb + (size_t)8192 * 1024;     // [B,S,D] bf16 (16MB)
  // total ws use: 88MB

  convert_x<<<8192, 256, 0, stream>>>(x, xb);
  pack_weights<<<dim3(16, 16, 4), 256, 0, stream>>>(wq, wk, wv, wo, wt_qkv, wt_o);
  gemm_bt<0><<<1536, 256, 0, stream>>>(xb, wt_qkv, bq, bk, bv, Qb, Kbuf, Vgb);
  flash_attn<<<256, 512, 0, stream>>>(Qb, Kbuf, Vgb, ctx);
  gemm_bt<1><<<512, 256, 0, stream>>>(ctx, wt_o, bo, nullptr, nullptr,
                                      d_out, nullptr, nullptr);
}

// Round 10
// 282.261 us; speedup vs baseline: 1.0062x; 1.0062x over previous
//
#include <hip/hip_runtime.h>
#include <stdint.h>

// Problem: B=4, S=2048, D=1024, H=16, HD=64. I/O fp32; internal compute bf16
// MFMA with fp32 accumulation.
// SCALE*log2(e) folded into wq^T and bq -> flash uses exp2 directly with a
// FIXED softmax max of 0 (shift-invariant; logits statically bounded ~|9|).
// Flash lineage: R9 (99.7) 16x16 reg-P. R12 setprio+dbuf REGRESSED (110.2).
// R13 2x occupancy: null. R14 32x32x16 MFMA (106.5): -67% MFMA instr -> null.
// R15 T14 async reg-staging (93.7, -12% CONFIRMED). R16 64 q/wave: null.
// R17 fragment-direct V image: null (95.0; conflicts unchanged 2.1M => they
// were K-side ~2-way, cheap). FOUR structural nulls at 93-95us => flash is at
// its structure floor (~723 TF, near m214 plain-HIP ladder) -- FROZEN.
// R18 (this round): non-flash pot is ~189us; ledger forces gemm<0> ~90us
// (~570 TF, 35% below m97-structure's 912). Suspect: launch_bounds(256,2)
// pins GEMMs at 2 blocks/CU; m97's 874-912 TF was measured at ~3 blocks/CU
// (m114: 3-block implicit wave-overlap hides the staging drain). Change:
// gemm_bt launch_bounds (256,2)->(256,3). Everything else frozen.

typedef __attribute__((ext_vector_type(8))) short bf16x8;
typedef __attribute__((ext_vector_type(4))) short bf16x4;
typedef __attribute__((ext_vector_type(4))) float f32x4;
typedef __attribute__((ext_vector_type(16))) float f32x16;
typedef __attribute__((ext_vector_type(4))) int i32x4;
typedef unsigned short u16;
typedef unsigned int u32;

#define AS1 __attribute__((address_space(1)))
#define AS3 __attribute__((address_space(3)))

#define SCALE_L2E 0.18033688011112042f  // 0.125 * log2(e)

__device__ __forceinline__ void gld_lds16(const void* g, void* l) {
  // async global->LDS DMA: lane i's 16B land at (wave-uniform) l + i*16
  __builtin_amdgcn_global_load_lds((const AS1 void*)g, (AS3 void*)l, 16, 0, 0);
}

__device__ __forceinline__ u16 f2bf(float f) {
  u32 x = __builtin_bit_cast(u32, f);
  x += 0x7fff + ((x >> 16) & 1);  // RNE
  return (u16)(x >> 16);
}

__device__ __forceinline__ u16 f2bf_fast(float a) {
#if __has_builtin(__builtin_amdgcn_cvt_pk_bf16_f32)
  auto v = __builtin_amdgcn_cvt_pk_bf16_f32(a, a);  // both halves = a: order-immune
  return (u16)(__builtin_bit_cast(u32, v) & 0xffffu);
#else
  return f2bf(a);
#endif
}

__device__ __forceinline__ u32 pk2(float a, float b) {  // lo16=a, hi16=b
#if __has_builtin(__builtin_amdgcn_cvt_pk_bf16_f32)
  return __builtin_bit_cast(u32, __builtin_amdgcn_cvt_pk_bf16_f32(a, b));
#else
  return (u32)f2bf(a) | ((u32)f2bf(b) << 16);
#endif
}

__device__ __forceinline__ float exp2_fast(float x) {
#if __has_builtin(__builtin_amdgcn_exp2f)
  return __builtin_amdgcn_exp2f(x);
#else
  return exp2f(x);
#endif
}

__device__ __forceinline__ f32x16 zero16() {
  f32x16 z;
#pragma unroll
  for (int i = 0; i < 16; ++i) z[i] = 0.f;
  return z;
}

// ---------------------------------------------------------------------------
// fp32 -> bf16 conversion of x (8M elements)
// ---------------------------------------------------------------------------
__global__ __launch_bounds__(256) void convert_x(const float* __restrict__ x,
                                                 u16* __restrict__ xb) {
  int i = (blockIdx.x * 256 + threadIdx.x) * 4;
  float4 v = *(const float4*)(x + i);
  ushort4 o;
  o.x = f2bf(v.x); o.y = f2bf(v.y); o.z = f2bf(v.z); o.w = f2bf(v.w);
  *(ushort4*)(xb + i) = o;
}

// ---------------------------------------------------------------------------
// Weight pack (fp32 [K][N] -> bf16 [N][K]); wq scaled by SCALE*log2(e)
// ---------------------------------------------------------------------------
__global__ __launch_bounds__(256) void pack_weights(
    const float* __restrict__ wq, const float* __restrict__ wk,
    const float* __restrict__ wv, const float* __restrict__ wo,
    u16* __restrict__ wt_qkv, u16* __restrict__ wt_o) {
  __shared__ float tile[64][65];
  int mat = blockIdx.z;
  const float* src = (mat == 0) ? wq : (mat == 1) ? wk : (mat == 2) ? wv : wo;
  int k0 = blockIdx.y * 64, j0 = blockIdx.x * 64;
  int t = threadIdx.x;
  int lr = t >> 6;   // 0..3
  int lc = t & 63;
#pragma unroll
  for (int it = 0; it < 16; ++it) {
    int r = it * 4 + lr;
    tile[r][lc] = src[(size_t)(k0 + r) * 1024 + j0 + lc];
  }
  __syncthreads();
  u16* dst = (mat == 3) ? wt_o : (wt_qkv + (size_t)mat * 1024 * 1024);
#pragma unroll
  for (int it = 0; it < 16; ++it) {
    int nl = it * 4 + lr;
    float v = tile[lc][nl];
    if (mat == 0) v *= SCALE_L2E;  // fold attention scale + log2(e)
    dst[(size_t)(j0 + nl) * 1024 + k0 + lc] = f2bf(v);
  }
}

// ---------------------------------------------------------------------------
// GEMM: C[M,N] = A[M,1024](bf16) x Bt[N,1024]^T(bf16) + bias(fp32).
// 128x128 tile, 4 waves 2x2, each wave 4x4 of 16x16x32 bf16 MFMA (m97 struct).
// 1D grid, XCD-swizzled for L2 locality. launch_bounds(256,3): 3 blocks/CU
// (m97's verified occupancy point; m114 overlap mechanism). VGPR cap ~170.
// MODE 0: N=3072 fused QKV.
//   Q,K -> row-major [B,S,D] bf16 (coalesced stores, same addressing as MODE 1)
//   V   -> fragment-direct chunked image for flash (per bh, 64-s chunk ci:
//          [slice(4)][hi(2)][d(64)][8 s-entries] bf16; entry holds
//          V[s = ci*64+slice*16 + {4hi..4hi+3, 8+4hi..8+4hi+3}][d] in order).
// MODE 1: N=1024; plain row-major fp32 out + bias
// ---------------------------------------------------------------------------
template <int MODE>
__global__ __launch_bounds__(256, 3) void gemm_bt(
    const u16* __restrict__ A, const u16* __restrict__ Bt,
    const float* __restrict__ bias0, const float* __restrict__ bias1,
    const float* __restrict__ bias2,
    void* __restrict__ out0v, void* __restrict__ out1v, void* __restrict__ out2v) {
  __shared__ u16 lA[128 * 32];  // [m][k] rows of 32 bf16 (64B)
  __shared__ u16 lB[128 * 32];  // [n][k]
  const int K = 1024;
  int tid = threadIdx.x;
  int wave = tid >> 6, lane = tid & 63;

  int bid = blockIdx.x;
  int m0, n0;
  if constexpr (MODE == 0) {
    int xcd = bid & 7, j = bid >> 3;      // 192 blocks per XCD
    n0 = (xcd * 3 + j % 3) * 128;         // XCD owns n-tiles 3x..3x+2 (768KB B)
    m0 = (j / 3) * 128;                   // consecutive j share m-tile
  } else {
    n0 = (bid & 7) * 128;                 // XCD owns 1 n-tile (256KB B)
    m0 = (bid >> 3) * 128;
  }
  int wm = (wave & 1) * 64, wn = (wave >> 1) * 64;

  f32x4 acc[4][4];
#pragma unroll
  for (int i = 0; i < 4; ++i)
#pragma unroll
    for (int j = 0; j < 4; ++j) acc[i][j] = f32x4{0.f, 0.f, 0.f, 0.f};

  int srow = lane >> 2;          // source row within 16-row stage
  int scol = (lane & 3) * 8;     // source col chunk within 32

  for (int k0 = 0; k0 < K; k0 += 32) {
#pragma unroll
    for (int c = 0; c < 2; ++c) {
      int rbase = wave * 32 + c * 16;
      gld_lds16(A + (size_t)(m0 + rbase + srow) * K + k0 + scol, lA + rbase * 32);
      gld_lds16(Bt + (size_t)(n0 + rbase + srow) * K + k0 + scol, lB + rbase * 32);
    }
    __syncthreads();
    bf16x8 af[4], bfr[4];
#pragma unroll
    for (int mt = 0; mt < 4; ++mt)
      af[mt] = *(const bf16x8*)(lA + (wm + mt * 16 + (lane & 15)) * 32 + (lane >> 4) * 8);
#pragma unroll
    for (int nt = 0; nt < 4; ++nt)
      bfr[nt] = *(const bf16x8*)(lB + (wn + nt * 16 + (lane & 15)) * 32 + (lane >> 4) * 8);
#pragma unroll
    for (int mt = 0; mt < 4; ++mt)
#pragma unroll
      for (int nt = 0; nt < 4; ++nt)
        acc[mt][nt] = __builtin_amdgcn_mfma_f32_16x16x32_bf16(af[mt], bfr[nt], acc[mt][nt], 0, 0, 0);
    __syncthreads();
  }

  // epilogue: C/D layout row=(lane>>4)*4+r, col=lane&15 (m89-verified)
  int rbase0 = m0 + wm + (lane >> 4) * 4;
  int cbase = n0 + wn + (lane & 15);
#pragma unroll
  for (int nt = 0; nt < 4; ++nt) {
    int col = cbase + nt * 16;
    if constexpr (MODE == 0) {
      int mat = col >> 10, j = col & 1023;
      const float* bp = (mat == 0) ? bias0 : (mat == 1) ? bias1 : bias2;
      float bv = bp[j];
      if (mat == 0) bv *= SCALE_L2E;
      if (mat == 2) {
        // V fragment-direct image: 4 consecutive s per lane -> one 8B half-entry
        // offset (u16) = bh*131072 + ci*4096 + slice*1024 + hi*512 + d*8 + half*4
        // where s_loc = s&63, slice = s_loc>>4, srem = s_loc&15 (mult of 4),
        // hi = (srem>>2)&1, half = srem>>3, d = hd.
        int h = j >> 6, hd = j & 63;
        u16* base = (u16*)out2v;
#pragma unroll
        for (int mt = 0; mt < 4; ++mt) {
          int row0 = rbase0 + mt * 16;  // multiple of 4, no b/s crossing
          int b = row0 >> 11, s = row0 & 2047;
          int ci = s >> 6, sl = s & 63;
          int slice = sl >> 4, srem = sl & 15;   // srem in {0,4,8,12}
          size_t off = (size_t)(b * 16 + h) * 131072 + ci * 4096 + slice * 1024
                     + ((srem >> 2) & 1) * 512 + hd * 8 + (srem >> 3) * 4;
          ushort4 pk;
          pk.x = f2bf_fast(acc[mt][nt][0] + bv);
          pk.y = f2bf_fast(acc[mt][nt][1] + bv);
          pk.z = f2bf_fast(acc[mt][nt][2] + bv);
          pk.w = f2bf_fast(acc[mt][nt][3] + bv);
          *(ushort4*)(base + off) = pk;
        }
      } else {
        // Q,K row-major [B,S,D]: coalesced (consecutive lanes -> consecutive j)
        u16* base = (mat == 0) ? (u16*)out0v : (u16*)out1v;
#pragma unroll
        for (int mt = 0; mt < 4; ++mt)
#pragma unroll
          for (int r = 0; r < 4; ++r) {
            int row = rbase0 + mt * 16 + r;
            base[(size_t)row * 1024 + j] = f2bf_fast(acc[mt][nt][r] + bv);
          }
      }
    } else {
      float bv = bias0[col];
      float* o = (float*)out0v;
#pragma unroll
      for (int mt = 0; mt < 4; ++mt)
#pragma unroll
        for (int r = 0; r < 4; ++r) {
          int row = rbase0 + mt * 16 + r;
          o[(size_t)row * 1024 + col] = acc[mt][nt][r] + bv;
        }
    }
  }
}

// ---------------------------------------------------------------------------
// Flash attention (R17, FROZEN): 32x32x16 MFMA + T14 async reg-staging +
// 64 q/wave + fragment-direct V image (b128 PV reads).
// Grid 256 (1 block/CU): block = (bh, 512 q-rows), 8 waves x 64 q.
// Per KV-64 iter:
//   issue global_load(t+1) -> VGPRs (K pre-swizzled source, V image linear)
//   compute(t): 2 s-32 blocks sb:
//     kf[4] read ONCE, feeds both q-tiles (qt=0,1): sa0/sa1 via 8 MFMA
//     P = exp2 in regs (per qt), packed to pu[qt][ss]
//     PV per 16-s slice ss, per d-half dh: ONE b128 V-frag read
//       (lV + (sb*2+ss)*1024 + hi*512 + (dh*32+ql)*8), already in pi-order;
//       2 MFMA (qt)
//   __syncthreads(); ds_write regs -> LDS (t+1); __syncthreads()
// Fixed-max softmax (max=0), final lsum reduce = 1 shfl_xor(32).
// ---------------------------------------------------------------------------
__global__ __launch_bounds__(512, 2) void flash_attn(
    const u16* __restrict__ Q, const u16* __restrict__ Kb,
    const u16* __restrict__ Vg, u16* __restrict__ ctx) {
  __shared__ u16 lK[2][64 * 32];  // [k-half][kv-row][32] xor-swizzled (8KB)
  __shared__ u16 lV[4096];        // fragment-direct image [slice][hi][d][8] (8KB)
  int tid = threadIdx.x, wave = tid >> 6, lane = tid & 63;  // wave 0..7

  int F = blockIdx.x;             // 256 flat blocks
  int xcd = F & 7, idx = F >> 3;  // 32 per XCD
  int bh = xcd * 8 + (idx >> 2);  // 8 bh per XCD; q-blocks of a bh adjacent
  int q0 = (idx & 3) * 512;
  int b = bh >> 4, h = bh & 15;
  const u16* Qp = Q + (size_t)b * 2048 * 1024 + h * 64;   // row-major head slice
  const u16* Kp = Kb + (size_t)b * 2048 * 1024 + h * 64;
  const u16* Vp = Vg + (size_t)bh * 131072;

  int ql = lane & 31;   // q (and K-row / V-d row) within 32-block
  int hi = lane >> 5;   // lane half

  // Q B-fragments (persistent): qf[qt][kk] = Q[q0+wave*64+qt*32+ql][kk*16+hi*8+j]
  bf16x8 qf[2][4];
#pragma unroll
  for (int qt = 0; qt < 2; ++qt) {
    const u16* qrow = Qp + (size_t)(q0 + wave * 64 + qt * 32 + ql) * 1024;
#pragma unroll
    for (int kk = 0; kk < 4; ++kk)
      qf[qt][kk] = *(const bf16x8*)(qrow + kk * 16 + hi * 8);
  }

  float lsum[2] = {0.f, 0.f};
  f32x16 o[2][2];  // [qt][dh]: O^T row d=32*dh+(r&3)+8*(r>>2)+4*hi, col q=ql
#pragma unroll
  for (int qt = 0; qt < 2; ++qt)
#pragma unroll
    for (int dh = 0; dh < 2; ++dh) o[qt][dh] = zero16();

  // Staging (T14 reg-staged; split over 8 waves, same layout as old DMA):
  // wave stages K half kk_w, rows rb*16..+16; lane covers row srow, chunk-pos
  // lane&3; source chunk = pos ^ ((row%16)>>1 & 3) (XOR swizzle); V linear.
  int srow = lane >> 2;
  int schunk = (((lane & 3) ^ ((lane >> 3) & 3)) * 8);
  int kk_w = wave & 1;
  int rb = wave >> 1;      // 0..3
  int stg_row = rb * 16 + srow;
  int rkey = ((lane & 15) >> 1) & 3;  // read-side swizzle key (row%16 == lane&15)

  const u16* gK = Kp + (size_t)stg_row * 1024 + kk_w * 32 + schunk;  // +s0*1024
  const u16* gV = Vp + wave * 512 + lane * 8;                        // +s0*64
  u16* wK = lK[kk_w] + rb * 512 + lane * 8;  // lane's 16B at base+lane*16 (u16*8)
  u16* wV = lV + wave * 512 + lane * 8;

  // prologue: tile 0 regs -> LDS
  i32x4 ldK = *(const i32x4*)gK;
  i32x4 ldV = *(const i32x4*)gV;
  *(i32x4*)wK = ldK;
  *(i32x4*)wV = ldV;
  __syncthreads();

  for (int s0 = 0; s0 < 2048; s0 += 64) {
    bool more = (s0 + 64 < 2048);  // wave-uniform
    if (more) {
      // issue t+1 loads now; latency hides under compute(t)
      ldK = *(const i32x4*)(gK + (size_t)(s0 + 64) * 1024);
      ldV = *(const i32x4*)(gV + (size_t)(s0 + 64) * 64);
    }

#pragma unroll
    for (int sb = 0; sb < 2; ++sb) {
      // K A-fragments (read once, feed both q-tiles):
      // lane holds s-row = sb*32+ql, k = kk*16 + hi*8 + j
      bf16x8 kf[4];
      int krb = (sb * 32 + ql) * 32;  // row base (u16)
#pragma unroll
      for (int kk = 0; kk < 4; ++kk)
        kf[kk] = *(const bf16x8*)(lK[kk >> 1] + krb + ((((kk & 1) << 1) | hi) ^ rkey) * 8);

      f32x16 sa0 = zero16(), sa1 = zero16();
#pragma unroll
      for (int kk = 0; kk < 4; ++kk) {
        sa0 = __builtin_amdgcn_mfma_f32_32x32x16_bf16(kf[kk], qf[0][kk], sa0, 0, 0, 0);
        sa1 = __builtin_amdgcn_mfma_f32_32x32x16_bf16(kf[kk], qf[1][kk], sa1, 0, 0, 0);
      }

      // softmax (fixed max 0, log2 units): reg r -> s_local = (r&3)+8*(r>>2)+4*hi
      // pack per qt into pu[qt][ss] (B-frag, register-native pi order)
      bf16x8 pu[2][2];
#pragma unroll
      for (int qt = 0; qt < 2; ++qt) {
        float p[16];
#pragma unroll
        for (int r = 0; r < 16; ++r)
          p[r] = exp2_fast(qt == 0 ? sa0[r] : sa1[r]);
        float a0 = (p[0] + p[1]) + (p[2] + p[3]);
        float a1 = (p[4] + p[5]) + (p[6] + p[7]);
        float a2 = (p[8] + p[9]) + (p[10] + p[11]);
        float a3 = (p[12] + p[13]) + (p[14] + p[15]);
        lsum[qt] += (a0 + a1) + (a2 + a3);
#pragma unroll
        for (int ss = 0; ss < 2; ++ss) {
          union { u32 w[4]; bf16x8 v; } pk_;
          pk_.w[0] = pk2(p[8 * ss + 0], p[8 * ss + 1]);
          pk_.w[1] = pk2(p[8 * ss + 2], p[8 * ss + 3]);
          pk_.w[2] = pk2(p[8 * ss + 4], p[8 * ss + 5]);
          pk_.w[3] = pk2(p[8 * ss + 6], p[8 * ss + 7]);
          pu[qt][ss] = pk_.v;
        }
      }

      // PV: per 16-s slice ss, per d-half dh: ONE b128 A-frag read from the
      // fragment-direct image (pi-order k-slots match register-native P).
#pragma unroll
      for (int ss = 0; ss < 2; ++ss) {
        int vbase = (sb * 2 + ss) * 1024 + hi * 512 + ql * 8;
#pragma unroll
        for (int dh = 0; dh < 2; ++dh) {
          bf16x8 vf = *(const bf16x8*)(lV + vbase + dh * 256);
          o[0][dh] = __builtin_amdgcn_mfma_f32_32x32x16_bf16(vf, pu[0][ss], o[0][dh], 0, 0, 0);
          o[1][dh] = __builtin_amdgcn_mfma_f32_32x32x16_bf16(vf, pu[1][ss], o[1][dh], 0, 0, 0);
        }
      }
    }

    __syncthreads();   // all waves done reading tile t; t+1 loads retired
    if (more) {
      *(i32x4*)wK = ldK;
      *(i32x4*)wV = ldV;
    }
    __syncthreads();   // t+1 LDS writes visible
  }

  // epilogue: lsum pairs live on lanes l and l^32 (same q) -> one shfl_xor;
  // normalize, write ctx[b][q][h][d], d = 32*dh + 8*(r>>2) + 4*hi + (r&3)
#pragma unroll
  for (int qt = 0; qt < 2; ++qt) {
    float rs = lsum[qt] + __shfl_xor(lsum[qt], 32);
    float inv = 1.0f / fmaxf(rs, 1e-30f);
    int q = q0 + wave * 64 + qt * 32 + ql;
    size_t rowbase = ((size_t)(b * 2048 + q) * 16 + h) * 64;
#pragma unroll
    for (int dh = 0; dh < 2; ++dh)
#pragma unroll
      for (int rr = 0; rr < 4; ++rr) {
        ushort4 pk;
        pk.x = f2bf_fast(o[qt][dh][4 * rr + 0] * inv);
        pk.y = f2bf_fast(o[qt][dh][4 * rr + 1] * inv);
        pk.z = f2bf_fast(o[qt][dh][4 * rr + 2] * inv);
        pk.w = f2bf_fast(o[qt][dh][4 * rr + 3] * inv);
        *(ushort4*)(ctx + rowbase + dh * 32 + rr * 8 + hi * 4) = pk;
      }
  }
}

// ---------------------------------------------------------------------------
extern "C" void kernel_launch(void* const* d_in, const int* in_sizes, int n_in,
                              void* d_out, int out_size, void* d_ws, size_t ws_size,
                              hipStream_t stream) {
  const float* x  = (const float*)d_in[0];
  const float* wq = (const float*)d_in[1];
  const float* bq = (const float*)d_in[2];
  const float* wk = (const float*)d_in[3];
  const float* bk = (const float*)d_in[4];
  const float* wv = (const float*)d_in[5];
  const float* bv = (const float*)d_in[6];
  const float* wo = (const float*)d_in[7];
  const float* bo = (const float*)d_in[8];

  u16* ws = (u16*)d_ws;
  u16* xb     = ws;                            // 8192*1024 bf16 (16MB)
  u16* wt_qkv = xb + (size_t)8192 * 1024;      // 3072*1024 (6MB)
  u16* wt_o   = wt_qkv + (size_t)3072 * 1024;  // 1024*1024 (2MB)
  u16* Qb     = wt_o + (size_t)1024 * 1024;    // row-major [B,S,D] (16MB)
  u16* Kbuf   = Qb + (size_t)8192 * 1024;      // row-major [B,S,D] (16MB)
  u16* Vgb    = Kbuf + (size_t)8192 * 1024;    // fragment-direct image (16MB)
  u16* ctx    = Vgb + (size_t)8192 * 1024;     // [B,S,D] bf16 (16MB)
  // total ws use: 88MB

  convert_x<<<8192, 256, 0, stream>>>(x, xb);
  pack_weights<<<dim3(16, 16, 4), 256, 0, stream>>>(wq, wk, wv, wo, wt_qkv, wt_o);
  gemm_bt<0><<<1536, 256, 0, stream>>>(xb, wt_qkv, bq, bk, bv, Qb, Kbuf, Vgb);
  flash_attn<<<256, 512, 0, stream>>>(Qb, Kbuf, Vgb, ctx);
  gemm_bt<1><<<512, 256, 0, stream>>>(ctx, wt_o, bo, nullptr, nullptr,
                                      d_out, nullptr, nullptr);
}